// Round 4
// baseline (291.133 us; speedup 1.0000x reference)
//
#include <hip/hip_runtime.h>
#include <math.h>

#define BSZ 2
#define SEQ 2048
#define DIM 2048
#define NH 32
#define NKV 8
#define HD 64
#define KVDIM 512

typedef short short8 __attribute__((ext_vector_type(8)));
typedef short short4v __attribute__((ext_vector_type(4)));
typedef float f32x4 __attribute__((ext_vector_type(4)));
typedef int i32x4 __attribute__((ext_vector_type(4)));

__device__ __forceinline__ short fbf(float x) {
    unsigned u = __float_as_uint(x);
    u = (u + 0x7fffu + ((u >> 16) & 1u)) >> 16;   // RNE f32->bf16
    return (short)u;
}

#define AS1(p) ((const __attribute__((address_space(1))) void*)(p))
#define AS3(p) ((__attribute__((address_space(3))) void*)(p))

#if defined(__has_builtin)
#if __has_builtin(__builtin_amdgcn_permlane16_swap) && __has_builtin(__builtin_amdgcn_permlane32_swap)
#define HAVE_PERMLANE 1
#endif
#endif

__device__ __forceinline__ float redmax4(float x) {
#ifdef HAVE_PERMLANE
    {
        auto p = __builtin_amdgcn_permlane16_swap(__float_as_uint(x), __float_as_uint(x), false, false);
        x = fmaxf(__uint_as_float(p[0]), __uint_as_float(p[1]));
    }
    {
        auto p = __builtin_amdgcn_permlane32_swap(__float_as_uint(x), __float_as_uint(x), false, false);
        x = fmaxf(__uint_as_float(p[0]), __uint_as_float(p[1]));
    }
#else
    x = fmaxf(x, __shfl_xor(x, 16));
    x = fmaxf(x, __shfl_xor(x, 32));
#endif
    return x;
}
__device__ __forceinline__ float redsum4(float x) {
#ifdef HAVE_PERMLANE
    {
        auto p = __builtin_amdgcn_permlane16_swap(__float_as_uint(x), __float_as_uint(x), false, false);
        x = __uint_as_float(p[0]) + __uint_as_float(p[1]);
    }
    {
        auto p = __builtin_amdgcn_permlane32_swap(__float_as_uint(x), __float_as_uint(x), false, false);
        x = __uint_as_float(p[0]) + __uint_as_float(p[1]);
    }
#else
    x += __shfl_xor(x, 16);
    x += __shfl_xor(x, 32);
#endif
    return x;
}

// ---------------------------------------------------------------------------
// prep: all fp32->bf16 conversions in ONE kernel.
// ---------------------------------------------------------------------------
__global__ __launch_bounds__(256) void prep(const float* __restrict__ X,
                                            const float* __restrict__ Wq,
                                            const float* __restrict__ Wk,
                                            const float* __restrict__ Wv,
                                            const float* __restrict__ Wo,
                                            short* __restrict__ Xb,
                                            short* __restrict__ Wqkv,
                                            short* __restrict__ Wob) {
    int i = blockIdx.x * 256 + threadIdx.x;
    const float* src; short* dst; int j;
    if (i < 2097152)      { src = X;  dst = Xb;             j = i; }
    else if (i < 3145728) { src = Wq; dst = Wqkv;           j = i - 2097152; }
    else if (i < 3407872) { src = Wk; dst = Wqkv + 4194304; j = i - 3145728; }
    else if (i < 3670016) { src = Wv; dst = Wqkv + 5242880; j = i - 3407872; }
    else                  { src = Wo; dst = Wob;            j = i - 3670016; }
    float4 f = ((const float4*)src)[j];
    short4v s = { fbf(f.x), fbf(f.y), fbf(f.z), fbf(f.w) };
    ((short4v*)dst)[j] = s;
}

// ---------------------------------------------------------------------------
// Fused QKV GEMM v3: 256x256 tile, BK=64, 8-phase schedule (4 phases/K-tile,
// 2 K-tiles' phases per dbuf cycle), counted vmcnt(6) at P4 only.
// Stage stream per K-tile group g: B0,B1,A0,A1 issued at {P2,P3,P4 of g-2,
// P1 of g-1} -> write-after-read safe (all B reads in P1, A reads in P1/P3),
// and vmcnt(6) at P4 forces K-tile kt+1 fully resident (3 halves in flight).
// Per phase: {ds_read subtile / 1 half-tile stage -> barrier -> setprio(1)
// -> 16 MFMA (one C-quadrant x K=64) -> setprio(0) -> barrier}.
// LDS 128 KiB: A [2 dbuf][2 half][128x64] | B same. Epilogue unchanged.
// ---------------------------------------------------------------------------
__global__ __launch_bounds__(512, 2) void gemm_qkv(const short* __restrict__ A,
                                                   const short* __restrict__ W,
                                                   const float* __restrict__ cosT,
                                                   const float* __restrict__ sinT,
                                                   short* __restrict__ Qo,
                                                   short* __restrict__ Ko,
                                                   short* __restrict__ Vo) {
    __shared__ short SM[65536];               // 128 KiB
    const int K = 2048;
    const int NT = 32;                        // K / 64
    const int tid = threadIdx.x;
    const int lane = tid & 63, wave = tid >> 6;
    const int l15 = lane & 15, quad = lane >> 4;
    const int wm = (wave >> 2) * 128;
    const int wn = (wave & 3) * 64;
    const int orig = blockIdx.x;
    const int wgid = (orig & 7) * 24 + (orig >> 3);   // bijective XCD swizzle
    const int by = wgid / 12, bx = wgid - by * 12;
    const int m0 = by * 256, n0 = bx * 256;

    const int cs0 = (quad ^ (l15 & 7)) * 8;           // K-chunk kh=0 (swizzled)
    const int cs1 = ((4 + quad) ^ (l15 & 7)) * 8;     // K-chunk kh=1
    const int halfA = wm >> 7;
    const int halfB = wn >> 7;
    const int rB0 = wn & 127;                          // 0 or 64 within B half

    int srow[2], spc[2];
#pragma unroll
    for (int v = 0; v < 2; ++v) {
        int s = v * 512 + tid;
        srow[v] = s >> 3;
        spc[v] = ((s & 7) ^ ((s >> 3) & 7)) * 8;
    }

    f32x4 acc[8][4] = {};

    auto stg = [&](int arr, int bbuf, int half, int kt2) {
        const short* gs = arr ? W : A;
        const int row0 = (arr ? n0 : m0) + half * 128;
        short* db = SM + arr * 32768 + bbuf * 16384 + half * 8192;
#pragma unroll
        for (int v = 0; v < 2; ++v)
            __builtin_amdgcn_global_load_lds(AS1(gs + (size_t)(row0 + srow[v]) * K + kt2 * 64 + spc[v]),
                                             AS3(db + (v * 512 + tid) * 8), 16, 0, 0);
    };

    // prologue: stream order B0,B1,A0,A1 per K-tile; 7 halves ahead
    stg(1, 0, 0, 0); stg(1, 0, 1, 0); stg(0, 0, 0, 0); stg(0, 0, 1, 0);
    stg(1, 1, 0, 1); stg(1, 1, 1, 1); stg(0, 1, 0, 1);
    asm volatile("s_waitcnt vmcnt(6)" ::: "memory");   // K-tile 0 resident
    __builtin_amdgcn_s_barrier();
    asm volatile("" ::: "memory");
    __builtin_amdgcn_sched_barrier(0);

    for (int kt = 0; kt < NT; ++kt) {
        const int b = kt & 1;
        const short* Ab = SM + b * 16384 + halfA * 8192;
        const short* Bb = SM + 32768 + b * 16384 + halfB * 8192;
        short8 bf_r[4][2], af_r[4][2];

        // ---- P1: read all B frags + A frags i0-3; stage A1(kt+1)
#pragma unroll
        for (int j = 0; j < 4; ++j) {
            const short* p = &Bb[(rB0 + j * 16 + l15) * 64];
            bf_r[j][0] = *(const short8*)(p + cs0);
            bf_r[j][1] = *(const short8*)(p + cs1);
        }
#pragma unroll
        for (int i = 0; i < 4; ++i) {
            const short* p = &Ab[(i * 16 + l15) * 64];
            af_r[i][0] = *(const short8*)(p + cs0);
            af_r[i][1] = *(const short8*)(p + cs1);
        }
        if (kt + 1 < NT) stg(0, (kt + 1) & 1, 1, kt + 1);
        __builtin_amdgcn_s_barrier();
        asm volatile("" ::: "memory");
        __builtin_amdgcn_sched_barrier(0);
        __builtin_amdgcn_s_setprio(1);
#pragma unroll
        for (int i = 0; i < 4; ++i)
#pragma unroll
            for (int j = 0; j < 2; ++j) {
                acc[i][j] = __builtin_amdgcn_mfma_f32_16x16x32_bf16(af_r[i][0], bf_r[j][0], acc[i][j], 0, 0, 0);
                acc[i][j] = __builtin_amdgcn_mfma_f32_16x16x32_bf16(af_r[i][1], bf_r[j][1], acc[i][j], 0, 0, 0);
            }
        __builtin_amdgcn_s_setprio(0);
        __builtin_amdgcn_s_barrier();
        asm volatile("" ::: "memory");
        __builtin_amdgcn_sched_barrier(0);

        // ---- P2: stage B0(kt+2); MFMA i0-3 x j2-3
        if (kt + 2 < NT) stg(1, b, 0, kt + 2);
        __builtin_amdgcn_s_barrier();
        asm volatile("" ::: "memory");
        __builtin_amdgcn_sched_barrier(0);
        __builtin_amdgcn_s_setprio(1);
#pragma unroll
        for (int i = 0; i < 4; ++i)
#pragma unroll
            for (int j = 2; j < 4; ++j) {
                acc[i][j] = __builtin_amdgcn_mfma_f32_16x16x32_bf16(af_r[i][0], bf_r[j][0], acc[i][j], 0, 0, 0);
                acc[i][j] = __builtin_amdgcn_mfma_f32_16x16x32_bf16(af_r[i][1], bf_r[j][1], acc[i][j], 0, 0, 0);
            }
        __builtin_amdgcn_s_setprio(0);
        __builtin_amdgcn_s_barrier();
        asm volatile("" ::: "memory");
        __builtin_amdgcn_sched_barrier(0);

        // ---- P3: read A frags i4-7 (reuse regs); stage B1(kt+2); MFMA i4-7 x j0-1
#pragma unroll
        for (int i = 0; i < 4; ++i) {
            const short* p = &Ab[((i + 4) * 16 + l15) * 64];
            af_r[i][0] = *(const short8*)(p + cs0);
            af_r[i][1] = *(const short8*)(p + cs1);
        }
        if (kt + 2 < NT) stg(1, b, 1, kt + 2);
        __builtin_amdgcn_s_barrier();
        asm volatile("" ::: "memory");
        __builtin_amdgcn_sched_barrier(0);
        __builtin_amdgcn_s_setprio(1);
#pragma unroll
        for (int i = 0; i < 4; ++i)
#pragma unroll
            for (int j = 0; j < 2; ++j) {
                acc[i + 4][j] = __builtin_amdgcn_mfma_f32_16x16x32_bf16(af_r[i][0], bf_r[j][0], acc[i + 4][j], 0, 0, 0);
                acc[i + 4][j] = __builtin_amdgcn_mfma_f32_16x16x32_bf16(af_r[i][1], bf_r[j][1], acc[i + 4][j], 0, 0, 0);
            }
        __builtin_amdgcn_s_setprio(0);
        __builtin_amdgcn_s_barrier();
        asm volatile("" ::: "memory");
        __builtin_amdgcn_sched_barrier(0);

        // ---- P4: stage A0(kt+2); vmcnt; MFMA i4-7 x j2-3
        if (kt + 2 < NT) stg(0, b, 0, kt + 2);
        if (kt < NT - 2)       asm volatile("s_waitcnt vmcnt(6)" ::: "memory");
        else if (kt == NT - 2) asm volatile("s_waitcnt vmcnt(0)" ::: "memory");
        __builtin_amdgcn_s_barrier();
        asm volatile("" ::: "memory");
        __builtin_amdgcn_sched_barrier(0);
        __builtin_amdgcn_s_setprio(1);
#pragma unroll
        for (int i = 0; i < 4; ++i)
#pragma unroll
            for (int j = 2; j < 4; ++j) {
                acc[i + 4][j] = __builtin_amdgcn_mfma_f32_16x16x32_bf16(af_r[i][0], bf_r[j][0], acc[i + 4][j], 0, 0, 0);
                acc[i + 4][j] = __builtin_amdgcn_mfma_f32_16x16x32_bf16(af_r[i][1], bf_r[j][1], acc[i + 4][j], 0, 0, 0);
            }
        __builtin_amdgcn_s_setprio(0);
        __builtin_amdgcn_s_barrier();
        asm volatile("" ::: "memory");
        __builtin_amdgcn_sched_barrier(0);
    }

    // ----------------- epilogue (unchanged; LDS free for per-wave reuse) -----
    const int n0r = n0 + wn;
    if (n0r < 2560) {
        short* dst; int heads, hh; float scale;
        if (n0r < 2048) { dst = Qo; heads = NH;  hh = n0r >> 6;          scale = 0.125f * 1.44269504088896f; }
        else            { dst = Ko; heads = NKV; hh = (n0r - 2048) >> 6; scale = 1.0f; }
        short* EB = SM + wave * 8192;
#pragma unroll
        for (int i = 0; i < 8; ++i)
#pragma unroll
            for (int r = 0; r < 4; ++r) {
                int rr = i * 16 + quad * 4 + r;
                int s = (m0 + wm + rr) & (SEQ - 1);
                int msk = ((rr >> 1) & 7) * 8;
#pragma unroll
                for (int jp = 0; jp < 2; ++jp) {
                    int d1 = jp * 16 + l15;
                    float c1 = cosT[s * HD + d1], s1v = sinT[s * HD + d1];
                    float x1 = acc[i][jp][r], x2 = acc[i][jp + 2][r];
                    EB[rr * 64 + (d1 ^ msk)]        = fbf((x1 * c1 - x2 * s1v) * scale);
                    EB[rr * 64 + ((d1 + 32) ^ msk)] = fbf((x2 * c1 + x1 * s1v) * scale);
                }
            }
#pragma unroll
        for (int t = 0; t < 16; ++t) {
            int rr = (lane >> 3) + t * 8;
            int c = lane & 7;
            short8 v8 = *(const short8*)&EB[rr * 64 + c * 8];
            int dchunk = c ^ ((rr >> 1) & 7);
            int mrow = m0 + wm + rr;
            int s = mrow & (SEQ - 1), bb = mrow >> 11;
            *(short8*)&dst[((size_t)(bb * SEQ + s) * heads + hh) * HD + dchunk * 8] = v8;
        }
    } else {
        const int hh = (n0r - 2560) >> 6;
#pragma unroll
        for (int i = 0; i < 8; ++i) {
            int mrow4 = m0 + wm + i * 16 + quad * 4;
            int s_abs = mrow4 & (SEQ - 1);
            int bb = mrow4 >> 11;
            int blk = s_abs >> 6, kk = s_abs & 63;
            int ob = ((kk >> 5) << 3) | (((kk >> 2) & 3) << 1) | ((kk >> 4) & 1);
#pragma unroll
            for (int j = 0; j < 4; ++j) {
                int d = j * 16 + l15;
                short4v pk = { fbf(acc[i][j][0]), fbf(acc[i][j][1]),
                               fbf(acc[i][j][2]), fbf(acc[i][j][3]) };
                *(short4v*)&Vo[(((size_t)(bb * NKV + hh) * HD + d) * SEQ) + blk * 64 + ob * 4] = pk;
            }
        }
    }
}

// ---------------------------------------------------------------------------
// bf16 NT GEMM v2 (Wo projection): BM=256 x BN=128, ring-4, counted vmcnt,
// 8 waves 4Mx2N (wave 64x64), grid 256 = 1 block/CU, XCD-swizzled.
// ---------------------------------------------------------------------------
__global__ __launch_bounds__(512, 2) void gemm_bf16(const short* __restrict__ A,
                                                    const short* __restrict__ W,
                                                    float* __restrict__ C,
                                                    int M, int N, int K) {
    __shared__ short SM[49152];               // 96 KiB: A-ring [4][8192] | B-ring [4][4096]
    const int NT = K >> 5;
    const int tid = threadIdx.x;
    const int lane = tid & 63, wave = tid >> 6;
    const int l15 = lane & 15, quad = lane >> 4;
    const int wm = (wave >> 1) * 64;
    const int wn = (wave & 1) * 64;
    const int orig = blockIdx.x;
    const int wgid = (orig & 7) * 32 + (orig >> 3);
    const int by = wgid >> 4, bx = wgid & 15;
    const int m0 = by * 256, n0 = bx * 128;

    size_t aoff[2]; int lslotA[2];
#pragma unroll
    for (int v = 0; v < 2; ++v) {
        int s = v * 512 + tid;
        int pr = s >> 3, w = s & 7;
        int row = (pr << 1) | (w & 1);
        int c = (w >> 1) ^ (pr & 3);
        aoff[v] = (size_t)(m0 + row) * K + c * 8;
        lslotA[v] = s * 8;
    }
    size_t boff; int lslotB;
    {
        int s = tid;
        int pr = s >> 3, w = s & 7;
        int row = (pr << 1) | (w & 1);
        int c = (w >> 1) ^ (pr & 3);
        boff = (size_t)(n0 + row) * K + c * 8;
        lslotB = s * 8;
    }
    const int r0a = wm + l15;
    const int pa = r0a >> 1;
    const int slotA0 = pa * 8 + (((quad ^ (pa & 3)) << 1) | (r0a & 1));
    const int r0b = wn + l15;
    const int pb = r0b >> 1;
    const int slotB0 = pb * 8 + (((quad ^ (pb & 3)) << 1) | (r0b & 1));

    f32x4 acc[4][4] = {};

    auto issue = [&](int t) {
        const int kb = t * 32;
        short* Ad = SM + (t & 3) * 8192;
        short* Bd = SM + 32768 + (t & 3) * 4096;
#pragma unroll
        for (int v = 0; v < 2; ++v)
            __builtin_amdgcn_global_load_lds(AS1(A + aoff[v] + kb), AS3(Ad + lslotA[v]), 16, 0, 0);
        __builtin_amdgcn_global_load_lds(AS1(W + boff + kb), AS3(Bd + lslotB), 16, 0, 0);
    };
    issue(0); issue(1); issue(2);
    asm volatile("s_waitcnt vmcnt(6)" ::: "memory");
    __builtin_amdgcn_s_barrier();
    asm volatile("" ::: "memory");
    __builtin_amdgcn_sched_barrier(0);

    for (int t = 0; t < NT; ++t) {
        if (t < NT - 3) issue(t + 3);
        const short* Ab = SM + (t & 3) * 8192;
        const short* Bb = SM + 32768 + (t & 3) * 4096;
        short8 af[4], bf8[4];
#pragma unroll
        for (int j = 0; j < 4; ++j)
            bf8[j] = *(const short8*)&Bb[(slotB0 + j * 64) * 8];
#pragma unroll
        for (int i = 0; i < 4; ++i)
            af[i] = *(const short8*)&Ab[(slotA0 + i * 64) * 8];
        __builtin_amdgcn_s_setprio(1);
#pragma unroll
        for (int i = 0; i < 4; ++i)
#pragma unroll
            for (int j = 0; j < 4; ++j)
                acc[i][j] = __builtin_amdgcn_mfma_f32_16x16x32_bf16(af[i], bf8[j], acc[i][j], 0, 0, 0);
        __builtin_amdgcn_s_setprio(0);
        if (t < NT - 3)       asm volatile("s_waitcnt vmcnt(6)" ::: "memory");
        else if (t == NT - 3) asm volatile("s_waitcnt vmcnt(3)" ::: "memory");
        else if (t == NT - 2) asm volatile("s_waitcnt vmcnt(0)" ::: "memory");
        __builtin_amdgcn_s_barrier();
        asm volatile("" ::: "memory");
        __builtin_amdgcn_sched_barrier(0);
    }
#pragma unroll
    for (int i = 0; i < 4; ++i)
#pragma unroll
        for (int j = 0; j < 4; ++j)
#pragma unroll
            for (int r = 0; r < 4; ++r)
                C[(size_t)(m0 + wm + i * 16 + quad * 4 + r) * N + n0 + wn + j * 16 + l15] = acc[i][j][r];
}

// ---------------------------------------------------------------------------
// flash4 v3 (unchanged): BK=64, 128 q-rows/block, 32 KiB LDS, 4 blocks/CU.
// ---------------------------------------------------------------------------
__global__ __launch_bounds__(512, 4) void flash4(const short* __restrict__ Qb,
                                                 const short* __restrict__ Kb,
                                                 const short* __restrict__ VT,
                                                 short* __restrict__ O) {
    __shared__ short Ks[2][64 * 64];
    __shared__ short Vs[2][64 * 64];
    const int d = blockIdx.x;
    const int bh = (d & 511) >> 3;
    const int qt = (d < 512) ? 15 - (d & 7) : (d & 7);
    const int b = bh >> 5, h = bh & 31, kvh = h >> 2;
    const int tid = threadIdx.x;
    const int wave = tid >> 6, lane = tid & 63;
    const int l15 = lane & 15, quad = lane >> 4;

    const short* qp = Qb + ((size_t)b * SEQ + qt * 128 + wave * 16 + l15) * DIM + h * HD + quad * 8;
    short8 qf0 = *(const short8*)qp;
    short8 qf1 = *(const short8*)(qp + 32);

    f32x4 o[4] = {};
    float m = -1e30f, l = 0.f;

    const short* Kbase = Kb + (size_t)b * SEQ * KVDIM + kvh * HD;
    const short* Vbase = VT + (size_t)(b * NKV + kvh) * HD * SEQ;

    const int srow = tid >> 3;
    const int scol = ((tid & 7) ^ (srow & 7)) * 8;
    auto issue = [&](int kt, int bi) {
        __builtin_amdgcn_global_load_lds(AS1(Kbase + (size_t)(kt * 64 + srow) * KVDIM + scol),
                                         AS3(&Ks[bi][tid * 8]), 16, 0, 0);
        __builtin_amdgcn_global_load_lds(AS1(Vbase + (size_t)srow * SEQ + kt * 64 + scol),
                                         AS3(&Vs[bi][tid * 8]), 16, 0, 0);
    };
    issue(0, 0);
    const int nkt = 2 * qt + 2;
    const int qmin = qt * 128 + wave * 16;
    for (int kt = 0; kt < nkt; ++kt) {
        const int bi = kt & 1;
        __builtin_amdgcn_s_barrier();
        asm volatile("" ::: "memory");
        if (kt + 1 < nkt) {
            issue(kt + 1, bi ^ 1);
            asm volatile("s_waitcnt vmcnt(2)" ::: "memory");
        } else {
            asm volatile("s_waitcnt vmcnt(0)" ::: "memory");
        }
        __builtin_amdgcn_sched_barrier(0);
        if (kt * 64 > qmin + 15) continue;

        f32x4 st[4] = {};
        __builtin_amdgcn_s_setprio(1);
#pragma unroll
        for (int kh = 0; kh < 2; ++kh) {
            const int cs = ((kh * 4 + quad) ^ (l15 & 7)) * 8;
#pragma unroll
            for (int nt = 0; nt < 4; ++nt) {
                short8 ka = *(const short8*)&Ks[bi][(nt * 16 + l15) * 64 + cs];
                st[nt] = __builtin_amdgcn_mfma_f32_16x16x32_bf16(ka, kh ? qf1 : qf0, st[nt], 0, 0, 0);
            }
        }
        __builtin_amdgcn_s_setprio(0);
        if (kt * 64 + 63 > qmin) {
            const int q = qmin + l15;
#pragma unroll
            for (int nt = 0; nt < 4; ++nt)
                if (kt * 64 + nt * 16 + 15 > qmin) {
#pragma unroll
                    for (int r = 0; r < 4; ++r)
                        if (kt * 64 + nt * 16 + quad * 4 + r > q) st[nt][r] = -1e30f;
                }
        }
        float mnt[4];
#pragma unroll
        for (int nt = 0; nt < 4; ++nt)
            mnt[nt] = fmaxf(fmaxf(fmaxf(st[nt][0], st[nt][1]), st[nt][2]), st[nt][3]);
        float mx = redmax4(fmaxf(fmaxf(mnt[0], mnt[1]), fmaxf(mnt[2], mnt[3])));

        const bool noskip = !__all(mx <= m);
        float mn = m;
        float al = 1.0f;
        float alr[4];
        if (noskip) {
            mn = fmaxf(m, mx);
            al = __builtin_amdgcn_exp2f(m - mn);
            m = mn;
#pragma unroll
            for (int r = 0; r < 4; ++r) alr[r] = __shfl(al, quad * 4 + r);
        }
        i32x4 aw[2];
        f32x4 rs4 = {};
#pragma unroll
        for (int nt = 0; nt < 4; ++nt) {
            f32x4 pv;
#pragma unroll
            for (int r = 0; r < 4; ++r) pv[r] = __builtin_amdgcn_exp2f(st[nt][r] - mn);
            rs4 += pv;
            unsigned u0 = __float_as_uint(pv[0]) + 0x8000u;
            unsigned u1 = __float_as_uint(pv[1]) + 0x8000u;
            unsigned u2 = __float_as_uint(pv[2]) + 0x8000u;
            unsigned u3 = __float_as_uint(pv[3]) + 0x8000u;
            aw[nt >> 1][(nt & 1) * 2 + 0] = (int)__builtin_amdgcn_perm(u1, u0, 0x07060302u);
            aw[nt >> 1][(nt & 1) * 2 + 1] = (int)__builtin_amdgcn_perm(u3, u2, 0x07060302u);
        }
        float rs = redsum4((rs4[0] + rs4[1]) + (rs4[2] + rs4[3]));
        l = l * al + rs;
        if (noskip) {
#pragma unroll
            for (int dt = 0; dt < 4; ++dt) {
                o[dt][0] *= alr[0]; o[dt][1] *= alr[1];
                o[dt][2] *= alr[2]; o[dt][3] *= alr[3];
            }
        }
        __builtin_amdgcn_s_setprio(1);
#pragma unroll
        for (int dt = 0; dt < 4; ++dt) {
            f32x4 t = o[dt];
#pragma unroll
            for (int kh = 0; kh < 2; ++kh) {
                const int slot = (kh * 4 + quad) ^ (l15 & 7);
                short8 vf = *(const short8*)&Vs[bi][(dt * 16 + l15) * 64 + slot * 8];
                t = __builtin_amdgcn_mfma_f32_16x16x32_bf16(__builtin_bit_cast(short8, aw[kh]), vf, t, 0, 0, 0);
            }
            o[dt] = t;
        }
        __builtin_amdgcn_s_setprio(0);
    }
    float li = 1.0f / l;
    float lr[4];
#pragma unroll
    for (int r = 0; r < 4; ++r) lr[r] = __shfl(li, quad * 4 + r);
    short* Oo = O + ((size_t)b * SEQ + qt * 128 + wave * 16 + quad * 4) * DIM + h * HD + l15;
#pragma unroll
    for (int r = 0; r < 4; ++r)
#pragma unroll
        for (int dt = 0; dt < 4; ++dt)
            Oo[(size_t)r * DIM + dt * 16] = fbf(o[dt][r] * lr[r]);
}

// ---------------------------------------------------------------------------
extern "C" void kernel_launch(void* const* d_in, const int* in_sizes, int n_in,
                              void* d_out, int out_size, void* d_ws, size_t ws_size,
                              hipStream_t stream) {
    const float* X    = (const float*)d_in[0];
    const float* cosT = (const float*)d_in[2];
    const float* sinT = (const float*)d_in[3];
    const float* Wq   = (const float*)d_in[4];
    const float* Wk   = (const float*)d_in[5];
    const float* Wv   = (const float*)d_in[6];
    const float* Wo   = (const float*)d_in[7];

    char* ws = (char*)d_ws;
    short* Xb    = (short*)(ws);                  // 16.8 MB; ATTb aliases after QKV gemm
    short* ATTb  = Xb;
    short* WQKVb = (short*)(ws + 16777216);       // 12.6 MB
    short* Wob   = (short*)(ws + 29360128);       // 8.4 MB
    short* Qbb   = (short*)(ws + 37748736);       // 16.8 MB
    short* Kbb   = (short*)(ws + 54525952);       // 4.2 MB (B*S*KVDIM bf16)
    short* VTb   = (short*)(ws + 58720256);       // 4.2 MB (B*NKV*HD*SEQ bf16)

    const int M = BSZ * SEQ;

    prep<<<dim3(18432), dim3(256), 0, stream>>>(X, Wq, Wk, Wv, Wo, Xb, WQKVb, Wob);
    gemm_qkv<<<dim3(192), dim3(512), 0, stream>>>(Xb, WQKVb, cosT, sinT, Qbb, Kbb, VTb);
    flash4<<<dim3(1024), dim3(512), 0, stream>>>(Qbb, Kbb, VTb, ATTb);
    gemm_bf16<<<dim3(256), dim3(512), 0, stream>>>(ATTb, Wob, (float*)d_out, M, DIM, DIM);
}